// Round 5
// baseline (436.464 us; speedup 1.0000x reference)
//
#include <hip/hip_runtime.h>
#include <cmath>

#define NN 4096
#define KK 32
#define DD 256
#define HH 128
#define G3 384   // 3*H
#define CH 16    // xw chunk steps staged in LDS

typedef __attribute__((ext_vector_type(8))) short short8;
typedef __attribute__((ext_vector_type(4))) float f32x4;

__device__ __forceinline__ unsigned short f2bf(float x) {
  unsigned int u = __float_as_uint(x);
  unsigned int r = (u + 0x7FFFu + ((u >> 16) & 1u)) >> 16;
  return (unsigned short)r;
}

// ---------------------------------------------------------------------------
// Kernel 1 (proven): per-cluster ordered lists, positions, lengths;
// block KK computes the weight-norm scale g/||v||.
// ---------------------------------------------------------------------------
__global__ void build_order_k(const int* __restrict__ labels,
                              const float* __restrict__ lin_v,
                              const float* __restrict__ lin_g,
                              int* __restrict__ order,
                              int* __restrict__ pos,
                              int* __restrict__ len,
                              float* __restrict__ scale) {
  const int c = blockIdx.x;
  const int lane = threadIdx.x;
  if (c < KK) {
    int count = 0;
    for (int base = 0; base < NN; base += 64) {
      const int i = base + lane;
      const bool f = (labels[i] == c);
      const unsigned long long m = __ballot(f);
      if (f) {
        const int p = count + __popcll(m & ((1ull << lane) - 1ull));
        order[c * NN + p] = i;
        pos[i] = p;
      }
      count += __popcll(m);
    }
    if (lane == 0) len[c] = count;
  } else {
    float s = 0.f;
    for (int j = lane; j < G3; j += 64) { const float v = lin_v[j]; s += v * v; }
    for (int off = 32; off; off >>= 1) s += __shfl_down(s, off);
    if (lane == 0) scale[0] = lin_g[0] / sqrtf(s);
  }
}

// ---------------------------------------------------------------------------
// Kernel 2 (proven): exclusive prefix over max(len,1) -> starts[KK+1]
// ---------------------------------------------------------------------------
__global__ void prefix_k(const int* __restrict__ len, int* __restrict__ starts) {
  if (threadIdx.x == 0) {
    int s = 0;
    for (int c = 0; c < KK; ++c) {
      starts[c] = s;
      const int l = len[c];
      s += (l > 0) ? l : 1;
    }
    starts[KK] = s;
  }
}

// ---------------------------------------------------------------------------
// Kernel 3 (proven): pack W_hh into bf16 HI/LO-residual B fragments.
// Layout: [layer][half][nt(24)][kt(4)][lane(64)][j(8)].
// ---------------------------------------------------------------------------
__global__ __launch_bounds__(256) void pack_whh_k(
    const float* __restrict__ W0, const float* __restrict__ W1,
    unsigned short* __restrict__ P) {
  const int gid = blockIdx.x * 256 + threadIdx.x;   // 2*2*24*4*64 = 24576
  if (gid >= 24576) return;
  const int lane = gid & 63;
  const int kt = (gid >> 6) & 3;
  const int nt = (gid >> 8) % 24;
  const int rest = (gid >> 8) / 24;                 // layer*2 + half
  const int half = rest & 1;
  const float* W = (rest >> 1) ? W1 : W0;
  const int n = nt * 16 + (lane & 15);
  const int kbase = kt * 32 + (lane >> 4) * 8;
  unsigned short* dst = P + (size_t)gid * 8;
#pragma unroll
  for (int j = 0; j < 8; ++j) {
    const float w = W[(size_t)n * HH + kbase + j];
    const unsigned short hi = f2bf(w);
    if (half == 0) {
      dst[j] = hi;
    } else {
      const float hif = __uint_as_float(((unsigned int)hi) << 16);
      dst[j] = f2bf(w - hif);
    }
  }
}

// ---------------------------------------------------------------------------
// Kernel 4/6 (proven): out[slot(i)][g] = bias[g] + sum_d X[i][d]*W[g][d]
// BM=128 x BN=64, BK=16, 256 threads, 8x4 micro-tile.
// ---------------------------------------------------------------------------
template<int DIN>
__global__ __launch_bounds__(256) void gemm_ih_k(
    const float* __restrict__ X, const float* __restrict__ W,
    const float* __restrict__ bias,
    const int* __restrict__ labels, const int* __restrict__ pos,
    const int* __restrict__ starts, const int* __restrict__ Mtot,
    float* __restrict__ out) {
  __shared__ float Xs[16][132];
  __shared__ float Ws[16][68];
  const int M = Mtot ? *Mtot : NN;
  const int i0 = blockIdx.x * 128;
  const int g0 = blockIdx.y * 64;
  const int t  = threadIdx.x;
  const int it = t & 15;
  const int gt = t >> 4;
  float acc[8][4] = {};
  for (int k0 = 0; k0 < DIN; k0 += 16) {
#pragma unroll
    for (int l = 0; l < 2; ++l) {
      const int u = t * 2 + l;
      const int r = u >> 2;
      const int cq = u & 3;
      const int gi = i0 + r;
      float4 f = make_float4(0.f, 0.f, 0.f, 0.f);
      if (gi < M) f = *(const float4*)(X + (size_t)gi * DIN + k0 + cq * 4);
      Xs[cq * 4 + 0][r] = f.x; Xs[cq * 4 + 1][r] = f.y;
      Xs[cq * 4 + 2][r] = f.z; Xs[cq * 4 + 3][r] = f.w;
    }
    {
      const int r = t >> 2;
      const int cq = t & 3;
      const float4 f = *(const float4*)(W + (size_t)(g0 + r) * DIN + k0 + cq * 4);
      Ws[cq * 4 + 0][r] = f.x; Ws[cq * 4 + 1][r] = f.y;
      Ws[cq * 4 + 2][r] = f.z; Ws[cq * 4 + 3][r] = f.w;
    }
    __syncthreads();
#pragma unroll
    for (int k = 0; k < 16; ++k) {
      float a[8], b[4];
#pragma unroll
      for (int x = 0; x < 8; ++x) a[x] = Xs[k][it * 8 + x];
#pragma unroll
      for (int y = 0; y < 4; ++y) b[y] = Ws[k][gt * 4 + y];
#pragma unroll
      for (int x = 0; x < 8; ++x)
#pragma unroll
        for (int y = 0; y < 4; ++y)
          acc[x][y] += a[x] * b[y];
    }
    __syncthreads();
  }
  const float4 bs = *(const float4*)(bias + g0 + gt * 4);
#pragma unroll
  for (int x = 0; x < 8; ++x) {
    const int gi = i0 + it * 8 + x;
    if (gi >= M) continue;
    const int slot = labels ? (starts[labels[gi]] + pos[gi]) : gi;
    float4 o;
    o.x = acc[x][0] + bs.x; o.y = acc[x][1] + bs.y;
    o.z = acc[x][2] + bs.z; o.w = acc[x][3] + bs.w;
    *(float4*)(out + (size_t)slot * G3 + g0 + gt * 4) = o;
  }
}

// ---------------------------------------------------------------------------
// Kernel 5/7: GRU recurrence via MFMA (4 waves/cluster), CHUNKED xw staging.
// xw rows for CH steps are bulk-copied into LDS at chunk start so the
// vmcnt(0) drain the compiler emits before each s_barrier is paid once per
// CH steps instead of every step. hw/hpack double-buffered by parity.
// hw = W_hi.(h_hi+h_lo) + W_lo.h_hi via two interleaved MFMA chains.
// ---------------------------------------------------------------------------
__global__ __launch_bounds__(256, 1) void gru_rec_mfma_k(
    const float* __restrict__ xw,              // sorted [Mtot+CH][384] fp32
    const unsigned short* __restrict__ packHi,
    const unsigned short* __restrict__ packLo,
    const float* __restrict__ b_hh,
    const float* __restrict__ b_ih,            // empty-cluster fallback or null
    const int* __restrict__ starts, const int* __restrict__ len,
    float* __restrict__ h_seq,                 // sorted [Mtot][128] or null
    float* __restrict__ h_final) {             // [KK][128] or null
  const int c = blockIdx.x;
  const int t = threadIdx.x;
  const int wv = t >> 6, lane = t & 63;
  // preload B fragments: wave wv owns n-tiles wv*6 .. wv*6+5
  short8 Bh[6][4], Bl[6][4];
#pragma unroll
  for (int i = 0; i < 6; ++i) {
    const int nt = wv * 6 + i;
#pragma unroll
    for (int kt = 0; kt < 4; ++kt) {
      const size_t idx = ((size_t)(nt * 4 + kt) * 64 + lane) * 8;
      Bh[i][kt] = *(const short8*)(packHi + idx);
      Bl[i][kt] = *(const short8*)(packLo + idx);
    }
  }
  const int L = len[c], start = starts[c];
  const int Lr = (L > 0) ? L : 1;
  const bool use_bih = (L == 0) && (b_ih != nullptr);
  __shared__ __align__(16) float xwbuf[CH * G3];           // 24 KB
  __shared__ __align__(16) unsigned short hpack[2][2][HH]; // [parity][hi/lo]
  __shared__ float hw[2][G3];                              // [parity]
  if (t < HH) { hpack[0][0][t] = 0; hpack[0][1][t] = 0; }
  float br = 0.f, bz = 0.f, bn = 0.f, h_own = 0.f;
  float fr = 0.f, fz = 0.f, fn = 0.f;                      // empty-cluster xw
  if (t < HH) {
    br = b_hh[t]; bz = b_hh[HH + t]; bn = b_hh[2 * HH + t];
    if (use_bih) { fr = b_ih[t]; fz = b_ih[HH + t]; fn = b_ih[2 * HH + t]; }
  }
  __syncthreads();
  const int q = lane >> 4;
  const int is_row0 = ((lane & 15) == 0) ? 0 : 1;   // row0 -> hi, others -> lo
  for (int step = 0; step < Lr; ++step) {
    const int par = step & 1;
    // ---- chunk staging: copy CH xw rows into LDS (uniform branch) --------
    if ((step & (CH - 1)) == 0) {
      const float4* src = (const float4*)(xw + (size_t)(start + step) * G3);
      float4* dst = (float4*)xwbuf;
#pragma unroll
      for (int u = 0; u < (CH * G3 / 4) / 256; ++u)
        dst[t + u * 256] = src[t + u * 256];
    }
    // ---- MFMA phase ------------------------------------------------------
    const unsigned short* hbase = hpack[par][is_row0];
    short8 A[4];
#pragma unroll
    for (int kt = 0; kt < 4; ++kt)
      A[kt] = *(const short8*)(hbase + kt * 32 + q * 8);
#pragma unroll
    for (int i = 0; i < 6; ++i) {
      f32x4 aH = {0.f, 0.f, 0.f, 0.f};
      f32x4 aL = {0.f, 0.f, 0.f, 0.f};
#pragma unroll
      for (int kt = 0; kt < 4; ++kt) {
        aH = __builtin_amdgcn_mfma_f32_16x16x32_bf16(A[kt], Bh[i][kt], aH, 0, 0, 0);
        aL = __builtin_amdgcn_mfma_f32_16x16x32_bf16(A[kt], Bl[i][kt], aL, 0, 0, 0);
      }
      // rows: aH[0]=W_hi.h_hi, aH[1]=W_hi.h_lo, aL[0]=W_lo.h_hi
      if (lane < 16) hw[par][(wv * 6 + i) * 16 + lane] = aH[0] + aH[1] + aL[0];
    }
    __syncthreads();
    // ---- gate phase (threads 0..127) -------------------------------------
    if (t < HH) {
      const float* xrow = xwbuf + (step & (CH - 1)) * G3;
      const float xr = use_bih ? fr : xrow[t];
      const float xz = use_bih ? fz : xrow[HH + t];
      const float xn = use_bih ? fn : xrow[2 * HH + t];
      const float ar = xr + br + hw[par][t];
      const float az = xz + bz + hw[par][HH + t];
      const float an = bn + hw[par][2 * HH + t];
      const float r = 1.f / (1.f + __expf(-ar));
      const float z = 1.f / (1.f + __expf(-az));
      float targ = xn + r * an;
      targ = fminf(fmaxf(targ, -15.f), 15.f);
      const float e2 = __expf(2.f * targ);
      const float n = (e2 - 1.f) / (e2 + 1.f);
      h_own = (1.f - z) * n + z * h_own;
      const unsigned short hi = f2bf(h_own);
      const float hif = __uint_as_float(((unsigned int)hi) << 16);
      hpack[par ^ 1][0][t] = hi;
      hpack[par ^ 1][1][t] = f2bf(h_own - hif);
      if (h_seq) h_seq[(size_t)(start + step) * HH + t] = h_own;
    }
    __syncthreads();
  }
  if (h_final && t < HH) h_final[(size_t)c * HH + t] = h_own;
}

// ---------------------------------------------------------------------------
// Kernel 8 (proven): one wave per sentence -> scores[i] = tanh(scale*dot + b)
// ---------------------------------------------------------------------------
__global__ __launch_bounds__(256) void score_k(const float* __restrict__ sent,
                                               const int* __restrict__ labels,
                                               const float* __restrict__ ce,
                                               const float* __restrict__ lin_v,
                                               const float* __restrict__ scale,
                                               const float* __restrict__ lin_b,
                                               float* __restrict__ scores) {
  const int wid = threadIdx.x >> 6;
  const int lane = threadIdx.x & 63;
  const int i = blockIdx.x * 4 + wid;
  const float4* s4 = (const float4*)(sent + (size_t)i * DD);
  const float4* v4 = (const float4*)lin_v;
  const float4 a = s4[lane];
  const float4 b = v4[lane];
  float acc = a.x * b.x + a.y * b.y + a.z * b.z + a.w * b.w;
  if (lane < 32) {
    const float4* c4 = (const float4*)(ce + (size_t)labels[i] * HH);
    const float4 hh = c4[lane];
    const float4 vb = v4[64 + lane];
    acc += hh.x * vb.x + hh.y * vb.y + hh.z * vb.z + hh.w * vb.w;
  }
  for (int off = 32; off; off >>= 1) acc += __shfl_down(acc, off);
  if (lane == 0) scores[i] = tanhf(scale[0] * acc + lin_b[0]);
}

// ---------------------------------------------------------------------------
// Kernel 9 (proven): per-cluster score sums (one wave per cluster)
// ---------------------------------------------------------------------------
__global__ void clu_k(const float* __restrict__ scores,
                      const int* __restrict__ order,
                      const int* __restrict__ len,
                      float* __restrict__ clu) {
  const int c = blockIdx.x;
  const int lane = threadIdx.x;
  const int L = len[c];
  float acc = 0.f;
  for (int p = lane; p < L; p += 64) acc += scores[order[c * NN + p]];
  for (int off = 32; off; off >>= 1) acc += __shfl_down(acc, off);
  if (lane == 0) clu[c] = acc;
}

// ---------------------------------------------------------------------------
// Kernel 10 (proven): final blend with position scores
// ---------------------------------------------------------------------------
__global__ void final_k(const float* __restrict__ scores,
                        const int* __restrict__ labels,
                        const float* __restrict__ clu,
                        float* __restrict__ out) {
  const int i = blockIdx.x * blockDim.x + threadIdx.x;
  if (i >= NN) return;
  float ps = expf(-(float)(i + 1) * 0.0625f);   // 1/4096^(1/3) == 1/16
  ps = fmaxf(0.5f, ps);
  out[i] = 0.5f * (scores[i] / clu[labels[i]]) + 0.5f * ps;
}

// ---------------------------------------------------------------------------
extern "C" void kernel_launch(void* const* d_in, const int* in_sizes, int n_in,
                              void* d_out, int out_size, void* d_ws, size_t ws_size,
                              hipStream_t stream) {
  const float* sent   = (const float*)d_in[0];
  const int*   labels = (const int*)d_in[1];
  const float* W_ih0  = (const float*)d_in[2];
  const float* W_hh0  = (const float*)d_in[3];
  const float* b_ih0  = (const float*)d_in[4];
  const float* b_hh0  = (const float*)d_in[5];
  const float* W_ih1  = (const float*)d_in[6];
  const float* W_hh1  = (const float*)d_in[7];
  const float* b_ih1  = (const float*)d_in[8];
  const float* b_hh1  = (const float*)d_in[9];
  const float* lin_v  = (const float*)d_in[10];
  const float* lin_g  = (const float*)d_in[11];
  const float* lin_b  = (const float*)d_in[12];
  float* out = (float*)d_out;

  char* ws = (char*)d_ws;
  size_t off = 0;
  auto alloc = [&](size_t bytes) -> void* {
    void* p = ws + off;
    off = (off + bytes + 255) & ~(size_t)255;
    return p;
  };
  int*   order  = (int*)  alloc((size_t)KK * NN * sizeof(int));
  int*   pos    = (int*)  alloc(NN * sizeof(int));
  int*   len    = (int*)  alloc(KK * sizeof(int));
  int*   starts = (int*)  alloc((KK + 1) * sizeof(int));
  float* scale  = (float*)alloc(sizeof(float));
  unsigned short* pack = (unsigned short*)alloc((size_t)24576 * 8 * sizeof(unsigned short));
  float* xw     = (float*)alloc((size_t)(NN + KK + CH) * G3 * sizeof(float));
  float* h1     = (float*)alloc((size_t)(NN + KK) * HH * sizeof(float));
  float* ce     = (float*)alloc((size_t)KK * HH * sizeof(float));
  float* scores = (float*)alloc(NN * sizeof(float));
  float* clu    = (float*)alloc(KK * sizeof(float));
  (void)ws_size; (void)in_sizes; (void)n_in; (void)out_size;

  const size_t packH = (size_t)24 * 4 * 64 * 8;   // ushorts per (layer,half)

  build_order_k<<<dim3(KK + 1), dim3(64), 0, stream>>>(labels, lin_v, lin_g,
                                                       order, pos, len, scale);
  prefix_k<<<dim3(1), dim3(64), 0, stream>>>(len, starts);
  pack_whh_k<<<dim3(96), dim3(256), 0, stream>>>(W_hh0, W_hh1, pack);
  gemm_ih_k<DD><<<dim3(32, 6), dim3(256), 0, stream>>>(
      sent, W_ih0, b_ih0, labels, pos, starts, (const int*)nullptr, xw);
  gru_rec_mfma_k<<<dim3(KK), dim3(256), 0, stream>>>(
      xw, pack, pack + packH, b_hh0, b_ih0, starts, len, h1, (float*)nullptr);
  gemm_ih_k<HH><<<dim3(33, 6), dim3(256), 0, stream>>>(
      h1, W_ih1, b_ih1, (const int*)nullptr, (const int*)nullptr,
      (const int*)nullptr, starts + KK, xw);
  gru_rec_mfma_k<<<dim3(KK), dim3(256), 0, stream>>>(
      xw, pack + 2 * packH, pack + 3 * packH, b_hh1, (const float*)nullptr,
      starts, len, (float*)nullptr, ce);
  score_k<<<dim3(NN / 4), dim3(256), 0, stream>>>(sent, labels, ce, lin_v,
                                                  scale, lin_b, scores);
  clu_k<<<dim3(KK), dim3(64), 0, stream>>>(scores, order, len, clu);
  final_k<<<dim3(16), dim3(256), 0, stream>>>(scores, labels, clu, out);
}

// Round 6
// 412.681 us; speedup vs baseline: 1.0576x; 1.0576x over previous
//
#include <hip/hip_runtime.h>
#include <cmath>

#define NN 4096
#define KK 32
#define DD 256
#define HH 128
#define G3 384   // 3*H
#define CH 16    // xw chunk steps staged in LDS

typedef __attribute__((ext_vector_type(8))) _Float16 h8;
typedef __attribute__((ext_vector_type(4))) float f32x4;

// ---------------------------------------------------------------------------
// Kernel 1 (proven): per-cluster ordered lists, positions, lengths;
// block KK computes the weight-norm scale g/||v||.
// ---------------------------------------------------------------------------
__global__ void build_order_k(const int* __restrict__ labels,
                              const float* __restrict__ lin_v,
                              const float* __restrict__ lin_g,
                              int* __restrict__ order,
                              int* __restrict__ pos,
                              int* __restrict__ len,
                              float* __restrict__ scale) {
  const int c = blockIdx.x;
  const int lane = threadIdx.x;
  if (c < KK) {
    int count = 0;
    for (int base = 0; base < NN; base += 64) {
      const int i = base + lane;
      const bool f = (labels[i] == c);
      const unsigned long long m = __ballot(f);
      if (f) {
        const int p = count + __popcll(m & ((1ull << lane) - 1ull));
        order[c * NN + p] = i;
        pos[i] = p;
      }
      count += __popcll(m);
    }
    if (lane == 0) len[c] = count;
  } else {
    float s = 0.f;
    for (int j = lane; j < G3; j += 64) { const float v = lin_v[j]; s += v * v; }
    for (int off = 32; off; off >>= 1) s += __shfl_down(s, off);
    if (lane == 0) scale[0] = lin_g[0] / sqrtf(s);
  }
}

// ---------------------------------------------------------------------------
// Kernel 2 (proven): exclusive prefix over max(len,1) -> starts[KK+1]
// ---------------------------------------------------------------------------
__global__ void prefix_k(const int* __restrict__ len, int* __restrict__ starts) {
  if (threadIdx.x == 0) {
    int s = 0;
    for (int c = 0; c < KK; ++c) {
      starts[c] = s;
      const int l = len[c];
      s += (l > 0) ? l : 1;
    }
    starts[KK] = s;
  }
}

// ---------------------------------------------------------------------------
// Kernel 3: pack W_hh (both layers) into f16 B-operand fragments of
// mfma_f32_16x16x32_f16 (B = W_hh^T). fp16 mantissa (11b) keeps W error
// ~2^-12 -> no lo-compensation chain needed.
// Layout: [layer][nt(24)][kt(4)][lane(64)][j(8)].
// B[k][n]: n = nt*16 + (lane&15), k = kt*32 + (lane>>4)*8 + j.
// ---------------------------------------------------------------------------
__global__ __launch_bounds__(256) void pack_whh_k(
    const float* __restrict__ W0, const float* __restrict__ W1,
    _Float16* __restrict__ P) {
  const int gid = blockIdx.x * 256 + threadIdx.x;   // 2*24*4*64 = 12288
  if (gid >= 12288) return;
  const int lane = gid & 63;
  const int kt = (gid >> 6) & 3;
  const int nt = (gid >> 8) % 24;
  const float* W = ((gid >> 8) / 24) ? W1 : W0;
  const int n = nt * 16 + (lane & 15);
  const int kbase = kt * 32 + (lane >> 4) * 8;
  _Float16* dst = P + (size_t)gid * 8;
#pragma unroll
  for (int j = 0; j < 8; ++j) dst[j] = (_Float16)W[(size_t)n * HH + kbase + j];
}

// ---------------------------------------------------------------------------
// Kernel 4/6 (proven): out[slot(i)][g] = bias[g] + sum_d X[i][d]*W[g][d]
// BM=128 x BN=64, BK=16, 256 threads, 8x4 micro-tile.
// ---------------------------------------------------------------------------
template<int DIN>
__global__ __launch_bounds__(256) void gemm_ih_k(
    const float* __restrict__ X, const float* __restrict__ W,
    const float* __restrict__ bias,
    const int* __restrict__ labels, const int* __restrict__ pos,
    const int* __restrict__ starts, const int* __restrict__ Mtot,
    float* __restrict__ out) {
  __shared__ float Xs[16][132];
  __shared__ float Ws[16][68];
  const int M = Mtot ? *Mtot : NN;
  const int i0 = blockIdx.x * 128;
  const int g0 = blockIdx.y * 64;
  const int t  = threadIdx.x;
  const int it = t & 15;
  const int gt = t >> 4;
  float acc[8][4] = {};
  for (int k0 = 0; k0 < DIN; k0 += 16) {
#pragma unroll
    for (int l = 0; l < 2; ++l) {
      const int u = t * 2 + l;
      const int r = u >> 2;
      const int cq = u & 3;
      const int gi = i0 + r;
      float4 f = make_float4(0.f, 0.f, 0.f, 0.f);
      if (gi < M) f = *(const float4*)(X + (size_t)gi * DIN + k0 + cq * 4);
      Xs[cq * 4 + 0][r] = f.x; Xs[cq * 4 + 1][r] = f.y;
      Xs[cq * 4 + 2][r] = f.z; Xs[cq * 4 + 3][r] = f.w;
    }
    {
      const int r = t >> 2;
      const int cq = t & 3;
      const float4 f = *(const float4*)(W + (size_t)(g0 + r) * DIN + k0 + cq * 4);
      Ws[cq * 4 + 0][r] = f.x; Ws[cq * 4 + 1][r] = f.y;
      Ws[cq * 4 + 2][r] = f.z; Ws[cq * 4 + 3][r] = f.w;
    }
    __syncthreads();
#pragma unroll
    for (int k = 0; k < 16; ++k) {
      float a[8], b[4];
#pragma unroll
      for (int x = 0; x < 8; ++x) a[x] = Xs[k][it * 8 + x];
#pragma unroll
      for (int y = 0; y < 4; ++y) b[y] = Ws[k][gt * 4 + y];
#pragma unroll
      for (int x = 0; x < 8; ++x)
#pragma unroll
        for (int y = 0; y < 4; ++y)
          acc[x][y] += a[x] * b[y];
    }
    __syncthreads();
  }
  const float4 bs = *(const float4*)(bias + g0 + gt * 4);
#pragma unroll
  for (int x = 0; x < 8; ++x) {
    const int gi = i0 + it * 8 + x;
    if (gi >= M) continue;
    const int slot = labels ? (starts[labels[gi]] + pos[gi]) : gi;
    float4 o;
    o.x = acc[x][0] + bs.x; o.y = acc[x][1] + bs.y;
    o.z = acc[x][2] + bs.z; o.w = acc[x][3] + bs.w;
    *(float4*)(out + (size_t)slot * G3 + g0 + gt * 4) = o;
  }
}

// ---------------------------------------------------------------------------
// Kernel 5/7: GRU recurrence, f16 MFMA, wave-local gates, ONE barrier/step.
// Wave w owns n-tiles {2w,2w+1, 8+2w,9+2w, 16+2w,17+2w}: after the 24 MFMAs
// lane l<16 holds the full (r,z,n) hw triple for gates t=32w+l and 32w+16+l
// in its D registers (rows 0,1 = h_hi,h_lo contributions) -> gate update is
// wave-local, no hw exchange. New h written as f16 hi/lo to parity-double-
// buffered LDS. xw staged in CH-step chunks (extra barrier per chunk).
// ---------------------------------------------------------------------------
__global__ __launch_bounds__(256, 1) void gru_rec_mfma_k(
    const float* __restrict__ xw,              // sorted [Mtot+CH][384] fp32
    const _Float16* __restrict__ pack,         // this layer's W_hh^T f16 frags
    const float* __restrict__ b_hh,
    const float* __restrict__ b_ih,            // empty-cluster fallback or null
    const int* __restrict__ starts, const int* __restrict__ len,
    float* __restrict__ h_seq,                 // sorted [Mtot][128] or null
    float* __restrict__ h_final) {             // [KK][128] or null
  const int c = blockIdx.x;
  const int t = threadIdx.x;
  const int wv = t >> 6, lane = t & 63;
  // preload B fragments (96 VGPRs/thread, loop-invariant)
  const int ntl0 = 2 * wv;
  h8 B[6][4];
#pragma unroll
  for (int i = 0; i < 6; ++i) {
    const int nt = (i >> 1) * 8 + ntl0 + (i & 1);   // 2w,2w+1,8+2w,9+2w,16+2w,17+2w
#pragma unroll
    for (int kt = 0; kt < 4; ++kt)
      B[i][kt] = *(const h8*)(pack + ((size_t)(nt * 4 + kt) * 64 + lane) * 8);
  }
  const int L = len[c], start = starts[c];
  const int Lr = (L > 0) ? L : 1;
  const bool use_bih = (L == 0) && (b_ih != nullptr);
  __shared__ __align__(16) float xwbuf[CH * G3];          // 24 KB
  __shared__ __align__(16) _Float16 hpack[2][2][HH];      // [parity][hi/lo]
  if (t < HH) { hpack[0][0][t] = (_Float16)0.f; hpack[0][1][t] = (_Float16)0.f; }
  // per-lane gate state (valid in lanes 0..15 of each wave)
  const int t0 = wv * 32 + lane, t1 = wv * 32 + 16 + lane;
  float br0 = 0.f, bz0 = 0.f, bn0 = 0.f, br1 = 0.f, bz1 = 0.f, bn1 = 0.f;
  float fr0 = 0.f, fz0 = 0.f, fn0 = 0.f, fr1 = 0.f, fz1 = 0.f, fn1 = 0.f;
  float h0 = 0.f, h1 = 0.f;
  if (lane < 16) {
    br0 = b_hh[t0]; bz0 = b_hh[HH + t0]; bn0 = b_hh[2 * HH + t0];
    br1 = b_hh[t1]; bz1 = b_hh[HH + t1]; bn1 = b_hh[2 * HH + t1];
    if (use_bih) {
      fr0 = b_ih[t0]; fz0 = b_ih[HH + t0]; fn0 = b_ih[2 * HH + t0];
      fr1 = b_ih[t1]; fz1 = b_ih[HH + t1]; fn1 = b_ih[2 * HH + t1];
    }
  }
  __syncthreads();
  const int q = lane >> 4;
  const int half_sel = ((lane & 15) == 0) ? 0 : 1;   // A row0 = h_hi, rows>=1 = h_lo
  for (int step = 0; step < Lr; ++step) {
    const int par = step & 1;
    // ---- chunk staging (all 256 threads) + chunk barrier -----------------
    if ((step & (CH - 1)) == 0) {
      const float4* src = (const float4*)(xw + (size_t)(start + step) * G3);
      float4* dst = (float4*)xwbuf;
#pragma unroll
      for (int u = 0; u < (CH * G3 / 4) / 256; ++u)
        dst[t + u * 256] = src[t + u * 256];
      __syncthreads();
    }
    // ---- A fragments from hpack[par] ------------------------------------
    const _Float16* hbase = hpack[par][half_sel];
    h8 A[4];
#pragma unroll
    for (int kt = 0; kt < 4; ++kt)
      A[kt] = *(const h8*)(hbase + kt * 32 + q * 8);
    // ---- 24 MFMAs: 6 independent chains of 4 ----------------------------
    f32x4 acc[6];
#pragma unroll
    for (int i = 0; i < 6; ++i) {
      f32x4 a = {0.f, 0.f, 0.f, 0.f};
#pragma unroll
      for (int kt = 0; kt < 4; ++kt)
        a = __builtin_amdgcn_mfma_f32_16x16x32_f16(A[kt], B[i][kt], a, 0, 0, 0);
      acc[i] = a;
    }
    // ---- wave-local gates (lanes 0..15) ----------------------------------
    if (lane < 16) {
      // D rows 0,1 (= W.h_hi, W.h_lo) live in regs 0,1 of lanes 0..15
      const float hwr0 = acc[0][0] + acc[0][1];
      const float hwr1 = acc[1][0] + acc[1][1];
      const float hwz0 = acc[2][0] + acc[2][1];
      const float hwz1 = acc[3][0] + acc[3][1];
      const float hwn0 = acc[4][0] + acc[4][1];
      const float hwn1 = acc[5][0] + acc[5][1];
      const float* xrow = xwbuf + (step & (CH - 1)) * G3;
      const float xr0 = use_bih ? fr0 : xrow[t0];
      const float xz0 = use_bih ? fz0 : xrow[HH + t0];
      const float xn0 = use_bih ? fn0 : xrow[2 * HH + t0];
      const float xr1 = use_bih ? fr1 : xrow[t1];
      const float xz1 = use_bih ? fz1 : xrow[HH + t1];
      const float xn1 = use_bih ? fn1 : xrow[2 * HH + t1];
      const float r0 = 1.f / (1.f + __expf(-(xr0 + br0 + hwr0)));
      const float z0 = 1.f / (1.f + __expf(-(xz0 + bz0 + hwz0)));
      const float r1 = 1.f / (1.f + __expf(-(xr1 + br1 + hwr1)));
      const float z1 = 1.f / (1.f + __expf(-(xz1 + bz1 + hwz1)));
      float tg0 = xn0 + r0 * (bn0 + hwn0);
      float tg1 = xn1 + r1 * (bn1 + hwn1);
      tg0 = fminf(fmaxf(tg0, -15.f), 15.f);
      tg1 = fminf(fmaxf(tg1, -15.f), 15.f);
      const float e0 = __expf(2.f * tg0), e1 = __expf(2.f * tg1);
      const float n0 = (e0 - 1.f) / (e0 + 1.f);
      const float n1 = (e1 - 1.f) / (e1 + 1.f);
      h0 = (1.f - z0) * n0 + z0 * h0;
      h1 = (1.f - z1) * n1 + z1 * h1;
      const _Float16 hi0 = (_Float16)h0, hi1 = (_Float16)h1;
      hpack[par ^ 1][0][t0] = hi0;
      hpack[par ^ 1][1][t0] = (_Float16)(h0 - (float)hi0);
      hpack[par ^ 1][0][t1] = hi1;
      hpack[par ^ 1][1][t1] = (_Float16)(h1 - (float)hi1);
      if (h_seq) {
        h_seq[(size_t)(start + step) * HH + t0] = h0;
        h_seq[(size_t)(start + step) * HH + t1] = h1;
      }
    }
    __syncthreads();
  }
  if (h_final && lane < 16) {
    h_final[(size_t)c * HH + t0] = h0;
    h_final[(size_t)c * HH + t1] = h1;
  }
}

// ---------------------------------------------------------------------------
// Kernel 8 (proven): one wave per sentence -> scores[i] = tanh(scale*dot + b)
// ---------------------------------------------------------------------------
__global__ __launch_bounds__(256) void score_k(const float* __restrict__ sent,
                                               const int* __restrict__ labels,
                                               const float* __restrict__ ce,
                                               const float* __restrict__ lin_v,
                                               const float* __restrict__ scale,
                                               const float* __restrict__ lin_b,
                                               float* __restrict__ scores) {
  const int wid = threadIdx.x >> 6;
  const int lane = threadIdx.x & 63;
  const int i = blockIdx.x * 4 + wid;
  const float4* s4 = (const float4*)(sent + (size_t)i * DD);
  const float4* v4 = (const float4*)lin_v;
  const float4 a = s4[lane];
  const float4 b = v4[lane];
  float acc = a.x * b.x + a.y * b.y + a.z * b.z + a.w * b.w;
  if (lane < 32) {
    const float4* c4 = (const float4*)(ce + (size_t)labels[i] * HH);
    const float4 hh = c4[lane];
    const float4 vb = v4[64 + lane];
    acc += hh.x * vb.x + hh.y * vb.y + hh.z * vb.z + hh.w * vb.w;
  }
  for (int off = 32; off; off >>= 1) acc += __shfl_down(acc, off);
  if (lane == 0) scores[i] = tanhf(scale[0] * acc + lin_b[0]);
}

// ---------------------------------------------------------------------------
// Kernel 9: fused per-cluster sum + final blend (one wave per cluster).
// Every sentence belongs to exactly one cluster -> full coverage of out.
// ---------------------------------------------------------------------------
__global__ void clufinal_k(const float* __restrict__ scores,
                           const int* __restrict__ order,
                           const int* __restrict__ len,
                           float* __restrict__ out) {
  const int c = blockIdx.x;
  const int lane = threadIdx.x;
  const int L = len[c];
  float acc = 0.f;
  for (int p = lane; p < L; p += 64) acc += scores[order[c * NN + p]];
  for (int off = 32; off; off >>= 1) acc += __shfl_down(acc, off);
  const float inv = 1.f / __shfl(acc, 0);
  for (int p = lane; p < L; p += 64) {
    const int i = order[c * NN + p];
    float ps = __expf(-(float)(i + 1) * 0.0625f);   // 1/4096^(1/3) == 1/16
    ps = fmaxf(0.5f, ps);
    out[i] = 0.5f * (scores[i] * inv) + 0.5f * ps;
  }
}

// ---------------------------------------------------------------------------
extern "C" void kernel_launch(void* const* d_in, const int* in_sizes, int n_in,
                              void* d_out, int out_size, void* d_ws, size_t ws_size,
                              hipStream_t stream) {
  const float* sent   = (const float*)d_in[0];
  const int*   labels = (const int*)d_in[1];
  const float* W_ih0  = (const float*)d_in[2];
  const float* W_hh0  = (const float*)d_in[3];
  const float* b_ih0  = (const float*)d_in[4];
  const float* b_hh0  = (const float*)d_in[5];
  const float* W_ih1  = (const float*)d_in[6];
  const float* W_hh1  = (const float*)d_in[7];
  const float* b_ih1  = (const float*)d_in[8];
  const float* b_hh1  = (const float*)d_in[9];
  const float* lin_v  = (const float*)d_in[10];
  const float* lin_g  = (const float*)d_in[11];
  const float* lin_b  = (const float*)d_in[12];
  float* out = (float*)d_out;

  char* ws = (char*)d_ws;
  size_t off = 0;
  auto alloc = [&](size_t bytes) -> void* {
    void* p = ws + off;
    off = (off + bytes + 255) & ~(size_t)255;
    return p;
  };
  int*   order  = (int*)  alloc((size_t)KK * NN * sizeof(int));
  int*   pos    = (int*)  alloc(NN * sizeof(int));
  int*   len    = (int*)  alloc(KK * sizeof(int));
  int*   starts = (int*)  alloc((KK + 1) * sizeof(int));
  float* scale  = (float*)alloc(sizeof(float));
  _Float16* pack = (_Float16*)alloc((size_t)12288 * 8 * sizeof(_Float16));
  float* xw     = (float*)alloc((size_t)(NN + KK + CH) * G3 * sizeof(float));
  float* h1     = (float*)alloc((size_t)(NN + KK) * HH * sizeof(float));
  float* ce     = (float*)alloc((size_t)KK * HH * sizeof(float));
  float* scores = (float*)alloc(NN * sizeof(float));
  (void)ws_size; (void)in_sizes; (void)n_in; (void)out_size;

  const size_t packL = (size_t)24 * 4 * 64 * 8;   // f16 elems per layer

  build_order_k<<<dim3(KK + 1), dim3(64), 0, stream>>>(labels, lin_v, lin_g,
                                                       order, pos, len, scale);
  prefix_k<<<dim3(1), dim3(64), 0, stream>>>(len, starts);
  pack_whh_k<<<dim3(48), dim3(256), 0, stream>>>(W_hh0, W_hh1, pack);
  gemm_ih_k<DD><<<dim3(32, 6), dim3(256), 0, stream>>>(
      sent, W_ih0, b_ih0, labels, pos, starts, (const int*)nullptr, xw);
  gru_rec_mfma_k<<<dim3(KK), dim3(256), 0, stream>>>(
      xw, pack, b_hh0, b_ih0, starts, len, h1, (float*)nullptr);
  gemm_ih_k<HH><<<dim3(33, 6), dim3(256), 0, stream>>>(
      h1, W_ih1, b_ih1, (const int*)nullptr, (const int*)nullptr,
      (const int*)nullptr, starts + KK, xw);
  gru_rec_mfma_k<<<dim3(KK), dim3(256), 0, stream>>>(
      xw, pack + packL, b_hh1, (const float*)nullptr, starts, len,
      (float*)nullptr, ce);
  score_k<<<dim3(NN / 4), dim3(256), 0, stream>>>(sent, labels, ce, lin_v,
                                                  scale, lin_b, scores);
  clufinal_k<<<dim3(KK), dim3(64), 0, stream>>>(scores, order, len, out);
}

// Round 7
// 320.527 us; speedup vs baseline: 1.3617x; 1.2875x over previous
//
#include <hip/hip_runtime.h>
#include <cmath>

#define NN 4096
#define KK 32
#define DD 256
#define HH 128
#define G3 384   // 3*H
#define CH 16    // xw0 chunk steps staged in LDS

typedef __attribute__((ext_vector_type(8))) _Float16 h8;
typedef __attribute__((ext_vector_type(4))) float f32x4;

// ---------------------------------------------------------------------------
// Kernel 1 (proven): per-cluster ordered lists, positions, lengths;
// block KK computes the weight-norm scale g/||v||.
// ---------------------------------------------------------------------------
__global__ void build_order_k(const int* __restrict__ labels,
                              const float* __restrict__ lin_v,
                              const float* __restrict__ lin_g,
                              int* __restrict__ order,
                              int* __restrict__ pos,
                              int* __restrict__ len,
                              float* __restrict__ scale) {
  const int c = blockIdx.x;
  const int lane = threadIdx.x;
  if (c < KK) {
    int count = 0;
    for (int base = 0; base < NN; base += 64) {
      const int i = base + lane;
      const bool f = (labels[i] == c);
      const unsigned long long m = __ballot(f);
      if (f) {
        const int p = count + __popcll(m & ((1ull << lane) - 1ull));
        order[c * NN + p] = i;
        pos[i] = p;
      }
      count += __popcll(m);
    }
    if (lane == 0) len[c] = count;
  } else {
    float s = 0.f;
    for (int j = lane; j < G3; j += 64) { const float v = lin_v[j]; s += v * v; }
    for (int off = 32; off; off >>= 1) s += __shfl_down(s, off);
    if (lane == 0) scale[0] = lin_g[0] / sqrtf(s);
  }
}

// ---------------------------------------------------------------------------
// Kernel 2 (proven): exclusive prefix over max(len,1) -> starts[KK+1]
// ---------------------------------------------------------------------------
__global__ void prefix_k(const int* __restrict__ len, int* __restrict__ starts) {
  if (threadIdx.x == 0) {
    int s = 0;
    for (int c = 0; c < KK; ++c) {
      starts[c] = s;
      const int l = len[c];
      s += (l > 0) ? l : 1;
    }
    starts[KK] = s;
  }
}

// ---------------------------------------------------------------------------
// Kernel 3: pack {W_hh0, W_ih1, W_hh1} (all 384x128) into f16 B-operand
// fragments of mfma_f32_16x16x32_f16 (B = W^T).
// Layout: [mat(3)][nt(24)][kt(4)][lane(64)][j(8)].
// B[k][n]: n = nt*16 + (lane&15), k = kt*32 + (lane>>4)*8 + j.
// ---------------------------------------------------------------------------
__global__ __launch_bounds__(256) void pack_w_k(
    const float* __restrict__ Whh0, const float* __restrict__ Wih1,
    const float* __restrict__ Whh1, _Float16* __restrict__ P) {
  const int gid = blockIdx.x * 256 + threadIdx.x;   // 3*24*4*64 = 18432
  if (gid >= 18432) return;
  const int lane = gid & 63;
  const int kt = (gid >> 6) & 3;
  const int nt = (gid >> 8) % 24;
  const int mat = (gid >> 8) / 24;
  const float* W = (mat == 0) ? Whh0 : (mat == 1 ? Wih1 : Whh1);
  const int n = nt * 16 + (lane & 15);
  const int kbase = kt * 32 + (lane >> 4) * 8;
  _Float16* dst = P + (size_t)gid * 8;
#pragma unroll
  for (int j = 0; j < 8; ++j) dst[j] = (_Float16)W[(size_t)n * HH + kbase + j];
}

// ---------------------------------------------------------------------------
// Kernel 4 (proven): out[slot(i)][g] = bias[g] + sum_d X[i][d]*W[g][d]
// BM=128 x BN=64, BK=16, 256 threads, 8x4 micro-tile. (layer-0 xw only)
// ---------------------------------------------------------------------------
__global__ __launch_bounds__(256) void gemm_ih_k(
    const float* __restrict__ X, const float* __restrict__ W,
    const float* __restrict__ bias,
    const int* __restrict__ labels, const int* __restrict__ pos,
    const int* __restrict__ starts, float* __restrict__ out) {
  __shared__ float Xs[16][132];
  __shared__ float Ws[16][68];
  const int i0 = blockIdx.x * 128;
  const int g0 = blockIdx.y * 64;
  const int t  = threadIdx.x;
  const int it = t & 15;
  const int gt = t >> 4;
  float acc[8][4] = {};
  for (int k0 = 0; k0 < DD; k0 += 16) {
#pragma unroll
    for (int l = 0; l < 2; ++l) {
      const int u = t * 2 + l;
      const int r = u >> 2;
      const int cq = u & 3;
      const float4 f = *(const float4*)(X + (size_t)(i0 + r) * DD + k0 + cq * 4);
      Xs[cq * 4 + 0][r] = f.x; Xs[cq * 4 + 1][r] = f.y;
      Xs[cq * 4 + 2][r] = f.z; Xs[cq * 4 + 3][r] = f.w;
    }
    {
      const int r = t >> 2;
      const int cq = t & 3;
      const float4 f = *(const float4*)(W + (size_t)(g0 + r) * DD + k0 + cq * 4);
      Ws[cq * 4 + 0][r] = f.x; Ws[cq * 4 + 1][r] = f.y;
      Ws[cq * 4 + 2][r] = f.z; Ws[cq * 4 + 3][r] = f.w;
    }
    __syncthreads();
#pragma unroll
    for (int k = 0; k < 16; ++k) {
      float a[8], b[4];
#pragma unroll
      for (int x = 0; x < 8; ++x) a[x] = Xs[k][it * 8 + x];
#pragma unroll
      for (int y = 0; y < 4; ++y) b[y] = Ws[k][gt * 4 + y];
#pragma unroll
      for (int x = 0; x < 8; ++x)
#pragma unroll
        for (int y = 0; y < 4; ++y)
          acc[x][y] += a[x] * b[y];
    }
    __syncthreads();
  }
  const float4 bs = *(const float4*)(bias + g0 + gt * 4);
#pragma unroll
  for (int x = 0; x < 8; ++x) {
    const int gi = i0 + it * 8 + x;
    const int slot = starts[labels[gi]] + pos[gi];
    float4 o;
    o.x = acc[x][0] + bs.x; o.y = acc[x][1] + bs.y;
    o.z = acc[x][2] + bs.z; o.w = acc[x][3] + bs.w;
    *(float4*)(out + (size_t)slot * G3 + g0 + gt * 4) = o;
  }
}

// ---------------------------------------------------------------------------
// Kernel 5: FUSED 2-layer GRU recurrence, one block (12 waves) per cluster,
// 1-step software pipeline (layer 1 lags layer 0 by one step):
//   waves 0-3 : hw0 = W_hh0 . h1(i-1), wave-local L0 gates -> h1(i)
//   waves 4-7 : xw1 = W_ih1 . h1(i-1)  -> LDS
//   waves 8-11: hw1 = W_hh1 . h2(i-2), wave-local L1 gates (+xw1) -> h2(i-1)
// Every wave: 24 MFMAs (6 n-tile chains x 4 k-tiles); 3 waves/SIMD; 72
// MFMAs/SIMD/step. h1/h2 as f16 hi+lo in parity-double-buffered LDS.
// 2 barriers/step. No h1 materialization, no middle gemm.
// ---------------------------------------------------------------------------
__global__ __launch_bounds__(768) void gru_fused_k(
    const float* __restrict__ xw0,          // sorted [Mtot+CH][384] fp32
    const _Float16* __restrict__ pack,      // [3][24][4][64][8] f16 frags
    const float* __restrict__ b_hh0, const float* __restrict__ b_ih0,
    const float* __restrict__ b_ih1, const float* __restrict__ b_hh1,
    const int* __restrict__ starts, const int* __restrict__ len,
    float* __restrict__ ce) {               // [KK][128] h2 final
  const int c = blockIdx.x;
  const int t = threadIdx.x;
  const int wv = t >> 6, lane = t & 63;
  const int group = wv >> 2;                // 0:L0-hw  1:L1-xw  2:L1-hw
  const int v = wv & 3;
  // ---- preload B fragments (96 VGPRs, loop-invariant) ---------------------
  h8 B[6][4];
  {
    const _Float16* mp = pack + (size_t)group * (24 * 4 * 64 * 8);
#pragma unroll
    for (int i = 0; i < 6; ++i) {
      const int nt = (i >> 1) * 8 + 2 * v + (i & 1);
#pragma unroll
      for (int kt = 0; kt < 4; ++kt)
        B[i][kt] = *(const h8*)(mp + ((size_t)(nt * 4 + kt) * 64 + lane) * 8);
    }
  }
  const int L = len[c], start = starts[c];
  const int Lr = (L > 0) ? L : 1;
  const bool use_bih0 = (L == 0);
  // ---- LDS ----------------------------------------------------------------
  __shared__ __align__(16) float xwbuf[CH * G3];         // 24 KB
  __shared__ __align__(16) _Float16 hp1[2][2][HH];       // [par][hi/lo]
  __shared__ __align__(16) _Float16 hp2[2][2][HH];
  __shared__ float xw1buf[G3];
  if (t < HH) {
    hp1[0][0][t] = (_Float16)0.f; hp1[0][1][t] = (_Float16)0.f;
    hp2[0][0][t] = (_Float16)0.f; hp2[0][1][t] = (_Float16)0.f;
    hp2[1][0][t] = (_Float16)0.f; hp2[1][1][t] = (_Float16)0.f;
  }
  // ---- per-lane gate constants (lanes 0..15) ------------------------------
  const int t0 = 32 * v + (lane & 15), t1 = t0 + 16;
  float bhr0 = 0.f, bhz0 = 0.f, bhn0 = 0.f, bhr1 = 0.f, bhz1 = 0.f, bhn1 = 0.f;
  float bir0 = 0.f, biz0 = 0.f, bin0 = 0.f, bir1 = 0.f, biz1 = 0.f, bin1 = 0.f;
  float ha = 0.f, hb = 0.f;                 // h state (h1 for g0, h2 for g2)
  if (lane < 16) {
    if (group == 0) {
      bhr0 = b_hh0[t0]; bhz0 = b_hh0[HH + t0]; bhn0 = b_hh0[2 * HH + t0];
      bhr1 = b_hh0[t1]; bhz1 = b_hh0[HH + t1]; bhn1 = b_hh0[2 * HH + t1];
      if (use_bih0) {
        bir0 = b_ih0[t0]; biz0 = b_ih0[HH + t0]; bin0 = b_ih0[2 * HH + t0];
        bir1 = b_ih0[t1]; biz1 = b_ih0[HH + t1]; bin1 = b_ih0[2 * HH + t1];
      }
    } else if (group == 2) {
      bhr0 = b_hh1[t0]; bhz0 = b_hh1[HH + t0]; bhn0 = b_hh1[2 * HH + t0];
      bhr1 = b_hh1[t1]; bhz1 = b_hh1[HH + t1]; bhn1 = b_hh1[2 * HH + t1];
      bir0 = b_ih1[t0]; biz0 = b_ih1[HH + t0]; bin0 = b_ih1[2 * HH + t0];
      bir1 = b_ih1[t1]; biz1 = b_ih1[HH + t1]; bin1 = b_ih1[2 * HH + t1];
    }
  }
  __syncthreads();
  const int q = lane >> 4;
  const int hs = ((lane & 15) == 0) ? 0 : 1;   // A row0 = h_hi, rows>=1 = h_lo
  for (int iter = 0; iter <= Lr; ++iter) {
    const int par = iter & 1;
    // ---- xw0 chunk staging (all 768 threads, 16 rows) --------------------
    if (iter < Lr && (iter & (CH - 1)) == 0 && !use_bih0) {
      const float4* src = (const float4*)(xw0 + (size_t)(start + iter) * G3);
      float4* dst = (float4*)xwbuf;
      dst[t] = src[t];
      dst[t + 768] = src[t + 768];
    }
    // ---- MFMA phase ------------------------------------------------------
    const bool mfma_on = (group == 0) ? (iter < Lr) : (iter >= 1);
    f32x4 acc[6];
    if (mfma_on) {
      const _Float16* hbase = (group == 2) ? hp2[par][hs] : hp1[par][hs];
      h8 A[4];
#pragma unroll
      for (int kt = 0; kt < 4; ++kt)
        A[kt] = *(const h8*)(hbase + kt * 32 + q * 8);
#pragma unroll
      for (int i = 0; i < 6; ++i) {
        f32x4 a = {0.f, 0.f, 0.f, 0.f};
#pragma unroll
        for (int kt = 0; kt < 4; ++kt)
          a = __builtin_amdgcn_mfma_f32_16x16x32_f16(A[kt], B[i][kt], a, 0, 0, 0);
        acc[i] = a;
      }
      if (group == 1 && lane < 16) {        // publish xw1 sums
        xw1buf[t0]          = acc[0][0] + acc[0][1];
        xw1buf[t1]          = acc[1][0] + acc[1][1];
        xw1buf[HH + t0]     = acc[2][0] + acc[2][1];
        xw1buf[HH + t1]     = acc[3][0] + acc[3][1];
        xw1buf[2 * HH + t0] = acc[4][0] + acc[4][1];
        xw1buf[2 * HH + t1] = acc[5][0] + acc[5][1];
      }
    }
    __syncthreads();   // B1: xw1 published; staging visible to gates
    // ---- gate phase (lanes 0..15 of gate-owning waves) -------------------
    if (lane < 16 && mfma_on && group != 1) {
      float xr0, xz0, xn0, xr1, xz1, xn1;
      if (group == 0) {
        const float* xrow = xwbuf + (iter & (CH - 1)) * G3;
        xr0 = use_bih0 ? bir0 : xrow[t0];
        xz0 = use_bih0 ? biz0 : xrow[HH + t0];
        xn0 = use_bih0 ? bin0 : xrow[2 * HH + t0];
        xr1 = use_bih0 ? bir1 : xrow[t1];
        xz1 = use_bih0 ? biz1 : xrow[HH + t1];
        xn1 = use_bih0 ? bin1 : xrow[2 * HH + t1];
      } else {
        xr0 = xw1buf[t0] + bir0;
        xz0 = xw1buf[HH + t0] + biz0;
        xn0 = xw1buf[2 * HH + t0] + bin0;
        xr1 = xw1buf[t1] + bir1;
        xz1 = xw1buf[HH + t1] + biz1;
        xn1 = xw1buf[2 * HH + t1] + bin1;
      }
      const float hwr0 = acc[0][0] + acc[0][1];
      const float hwr1 = acc[1][0] + acc[1][1];
      const float hwz0 = acc[2][0] + acc[2][1];
      const float hwz1 = acc[3][0] + acc[3][1];
      const float hwn0 = acc[4][0] + acc[4][1];
      const float hwn1 = acc[5][0] + acc[5][1];
      const float r0 = 1.f / (1.f + __expf(-(xr0 + bhr0 + hwr0)));
      const float z0 = 1.f / (1.f + __expf(-(xz0 + bhz0 + hwz0)));
      const float r1 = 1.f / (1.f + __expf(-(xr1 + bhr1 + hwr1)));
      const float z1 = 1.f / (1.f + __expf(-(xz1 + bhz1 + hwz1)));
      float tg0 = xn0 + r0 * (bhn0 + hwn0);
      float tg1 = xn1 + r1 * (bhn1 + hwn1);
      tg0 = fminf(fmaxf(tg0, -15.f), 15.f);
      tg1 = fminf(fmaxf(tg1, -15.f), 15.f);
      const float e0 = __expf(2.f * tg0), e1 = __expf(2.f * tg1);
      const float n0 = (e0 - 1.f) / (e0 + 1.f);
      const float n1 = (e1 - 1.f) / (e1 + 1.f);
      ha = (1.f - z0) * n0 + z0 * ha;
      hb = (1.f - z1) * n1 + z1 * hb;
      const _Float16 hiA = (_Float16)ha, hiB = (_Float16)hb;
      _Float16 (*hp)[HH] = (group == 0) ? hp1[par ^ 1] : hp2[par ^ 1];
      hp[0][t0] = hiA; hp[1][t0] = (_Float16)(ha - (float)hiA);
      hp[0][t1] = hiB; hp[1][t1] = (_Float16)(hb - (float)hiB);
    }
    __syncthreads();   // B2: hpacks ready for next iter; xw1buf reusable
  }
  if (group == 2 && lane < 16) {
    ce[(size_t)c * HH + t0] = ha;
    ce[(size_t)c * HH + t1] = hb;
  }
}

// ---------------------------------------------------------------------------
// Kernel 6 (proven): one wave per sentence -> scores[i] = tanh(scale*dot + b)
// ---------------------------------------------------------------------------
__global__ __launch_bounds__(256) void score_k(const float* __restrict__ sent,
                                               const int* __restrict__ labels,
                                               const float* __restrict__ ce,
                                               const float* __restrict__ lin_v,
                                               const float* __restrict__ scale,
                                               const float* __restrict__ lin_b,
                                               float* __restrict__ scores) {
  const int wid = threadIdx.x >> 6;
  const int lane = threadIdx.x & 63;
  const int i = blockIdx.x * 4 + wid;
  const float4* s4 = (const float4*)(sent + (size_t)i * DD);
  const float4* v4 = (const float4*)lin_v;
  const float4 a = s4[lane];
  const float4 b = v4[lane];
  float acc = a.x * b.x + a.y * b.y + a.z * b.z + a.w * b.w;
  if (lane < 32) {
    const float4* c4 = (const float4*)(ce + (size_t)labels[i] * HH);
    const float4 hh = c4[lane];
    const float4 vb = v4[64 + lane];
    acc += hh.x * vb.x + hh.y * vb.y + hh.z * vb.z + hh.w * vb.w;
  }
  for (int off = 32; off; off >>= 1) acc += __shfl_down(acc, off);
  if (lane == 0) scores[i] = tanhf(scale[0] * acc + lin_b[0]);
}

// ---------------------------------------------------------------------------
// Kernel 7 (proven): fused per-cluster sum + final blend (one wave/cluster)
// ---------------------------------------------------------------------------
__global__ void clufinal_k(const float* __restrict__ scores,
                           const int* __restrict__ order,
                           const int* __restrict__ len,
                           float* __restrict__ out) {
  const int c = blockIdx.x;
  const int lane = threadIdx.x;
  const int L = len[c];
  float acc = 0.f;
  for (int p = lane; p < L; p += 64) acc += scores[order[c * NN + p]];
  for (int off = 32; off; off >>= 1) acc += __shfl_down(acc, off);
  const float inv = 1.f / __shfl(acc, 0);
  for (int p = lane; p < L; p += 64) {
    const int i = order[c * NN + p];
    float ps = __expf(-(float)(i + 1) * 0.0625f);   // 1/4096^(1/3) == 1/16
    ps = fmaxf(0.5f, ps);
    out[i] = 0.5f * (scores[i] * inv) + 0.5f * ps;
  }
}

// ---------------------------------------------------------------------------
extern "C" void kernel_launch(void* const* d_in, const int* in_sizes, int n_in,
                              void* d_out, int out_size, void* d_ws, size_t ws_size,
                              hipStream_t stream) {
  const float* sent   = (const float*)d_in[0];
  const int*   labels = (const int*)d_in[1];
  const float* W_ih0  = (const float*)d_in[2];
  const float* W_hh0  = (const float*)d_in[3];
  const float* b_ih0  = (const float*)d_in[4];
  const float* b_hh0  = (const float*)d_in[5];
  const float* W_ih1  = (const float*)d_in[6];
  const float* W_hh1  = (const float*)d_in[7];
  const float* b_ih1  = (const float*)d_in[8];
  const float* b_hh1  = (const float*)d_in[9];
  const float* lin_v  = (const float*)d_in[10];
  const float* lin_g  = (const float*)d_in[11];
  const float* lin_b  = (const float*)d_in[12];
  float* out = (float*)d_out;

  char* ws = (char*)d_ws;
  size_t off = 0;
  auto alloc = [&](size_t bytes) -> void* {
    void* p = ws + off;
    off = (off + bytes + 255) & ~(size_t)255;
    return p;
  };
  int*   order  = (int*)  alloc((size_t)KK * NN * sizeof(int));
  int*   pos    = (int*)  alloc(NN * sizeof(int));
  int*   len    = (int*)  alloc(KK * sizeof(int));
  int*   starts = (int*)  alloc((KK + 1) * sizeof(int));
  float* scale  = (float*)alloc(sizeof(float));
  _Float16* pack = (_Float16*)alloc((size_t)18432 * 8 * sizeof(_Float16));
  float* xw     = (float*)alloc((size_t)(NN + KK + CH) * G3 * sizeof(float));
  float* ce     = (float*)alloc((size_t)KK * HH * sizeof(float));
  float* scores = (float*)alloc(NN * sizeof(float));
  (void)ws_size; (void)in_sizes; (void)n_in; (void)out_size;

  build_order_k<<<dim3(KK + 1), dim3(64), 0, stream>>>(labels, lin_v, lin_g,
                                                       order, pos, len, scale);
  prefix_k<<<dim3(1), dim3(64), 0, stream>>>(len, starts);
  pack_w_k<<<dim3(72), dim3(256), 0, stream>>>(W_hh0, W_ih1, W_hh1, pack);
  gemm_ih_k<<<dim3(32, 6), dim3(256), 0, stream>>>(
      sent, W_ih0, b_ih0, labels, pos, starts, xw);
  gru_fused_k<<<dim3(KK), dim3(768), 0, stream>>>(
      xw, pack, b_hh0, b_ih0, b_ih1, b_hh1, starts, len, ce);
  score_k<<<dim3(NN / 4), dim3(256), 0, stream>>>(sent, labels, ce, lin_v,
                                                  scale, lin_b, scores);
  clufinal_k<<<dim3(KK), dim3(64), 0, stream>>>(scores, order, len, out);
}

// Round 8
// 314.556 us; speedup vs baseline: 1.3876x; 1.0190x over previous
//
#include <hip/hip_runtime.h>
#include <cmath>

#define NN 4096
#define KK 32
#define DD 256
#define HH 128
#define G3 384   // 3*H
#define CH 16    // xw0 chunk steps staged in LDS

typedef __attribute__((ext_vector_type(8))) _Float16 h8;
typedef __attribute__((ext_vector_type(4))) float f32x4;

// ---------------------------------------------------------------------------
// Kernel 1: fused setup. Block 0: per-cluster ordered lists (16 waves x 2
// clusters), in-wave prefix -> starts, weight-norm scale. Blocks 1..18: pack
// {W_hh0, W_ih1, W_hh1} into f16 B-fragments of mfma_f32_16x16x32_f16.
// Pack layout: [mat(3)][nt(24)][kt(4)][lane(64)][j(8)];
// B[k][n]: n = nt*16 + (lane&15), k = kt*32 + (lane>>4)*8 + j.
// ---------------------------------------------------------------------------
__global__ __launch_bounds__(1024) void setup_k(
    const int* __restrict__ labels, const float* __restrict__ lin_v,
    const float* __restrict__ lin_g,
    const float* __restrict__ Whh0, const float* __restrict__ Wih1,
    const float* __restrict__ Whh1,
    int* __restrict__ order, int* __restrict__ pos, int* __restrict__ len,
    int* __restrict__ starts, float* __restrict__ scale,
    _Float16* __restrict__ P) {
  if (blockIdx.x != 0) {
    const int gid = (int)(blockIdx.x - 1) * 1024 + threadIdx.x;  // 3*24*4*64=18432
    if (gid >= 18432) return;
    const int lane = gid & 63;
    const int kt = (gid >> 6) & 3;
    const int nt = (gid >> 8) % 24;
    const int mat = (gid >> 8) / 24;
    const float* W = (mat == 0) ? Whh0 : (mat == 1 ? Wih1 : Whh1);
    const int n = nt * 16 + (lane & 15);
    const int kbase = kt * 32 + (lane >> 4) * 8;
    _Float16* dst = P + (size_t)gid * 8;
#pragma unroll
    for (int j = 0; j < 8; ++j) dst[j] = (_Float16)W[(size_t)n * HH + kbase + j];
    return;
  }
  const int t = threadIdx.x;
  const int wv = t >> 6, lane = t & 63;
  __shared__ int lens_s[KK];
  for (int cc = 0; cc < 2; ++cc) {
    const int c = wv * 2 + cc;
    int count = 0;
    for (int base = 0; base < NN; base += 64) {
      const int i = base + lane;
      const bool f = (labels[i] == c);
      const unsigned long long m = __ballot(f);
      if (f) {
        const int p = count + __popcll(m & ((1ull << lane) - 1ull));
        order[c * NN + p] = i;
        pos[i] = p;
      }
      count += __popcll(m);
    }
    if (lane == 0) { lens_s[c] = count; len[c] = count; }
  }
  __syncthreads();
  if (wv == 0) {
    int lm = 0;
    if (lane < KK) { const int l = lens_s[lane]; lm = (l > 0) ? l : 1; }
    int inc = lm;
    for (int off = 1; off < KK; off <<= 1) {
      const int o = __shfl_up(inc, off);
      if (lane >= off) inc += o;
    }
    if (lane < KK) starts[lane] = inc - lm;
    if (lane == KK - 1) starts[KK] = inc;
  } else if (wv == 1) {
    float s = 0.f;
    for (int j = lane; j < G3; j += 64) { const float v = lin_v[j]; s += v * v; }
    for (int off = 32; off; off >>= 1) s += __shfl_down(s, off);
    if (lane == 0) scale[0] = lin_g[0] / sqrtf(s);
  }
}

// ---------------------------------------------------------------------------
// Kernel 2 (proven): out[slot(i)][g] = bias[g] + sum_d X[i][d]*W[g][d]
// BM=128 x BN=64, BK=16, 256 threads, 8x4 micro-tile. (layer-0 xw only)
// ---------------------------------------------------------------------------
__global__ __launch_bounds__(256) void gemm_ih_k(
    const float* __restrict__ X, const float* __restrict__ W,
    const float* __restrict__ bias,
    const int* __restrict__ labels, const int* __restrict__ pos,
    const int* __restrict__ starts, float* __restrict__ out) {
  __shared__ float Xs[16][132];
  __shared__ float Ws[16][68];
  const int i0 = blockIdx.x * 128;
  const int g0 = blockIdx.y * 64;
  const int t  = threadIdx.x;
  const int it = t & 15;
  const int gt = t >> 4;
  float acc[8][4] = {};
  for (int k0 = 0; k0 < DD; k0 += 16) {
#pragma unroll
    for (int l = 0; l < 2; ++l) {
      const int u = t * 2 + l;
      const int r = u >> 2;
      const int cq = u & 3;
      const float4 f = *(const float4*)(X + (size_t)(i0 + r) * DD + k0 + cq * 4);
      Xs[cq * 4 + 0][r] = f.x; Xs[cq * 4 + 1][r] = f.y;
      Xs[cq * 4 + 2][r] = f.z; Xs[cq * 4 + 3][r] = f.w;
    }
    {
      const int r = t >> 2;
      const int cq = t & 3;
      const float4 f = *(const float4*)(W + (size_t)(g0 + r) * DD + k0 + cq * 4);
      Ws[cq * 4 + 0][r] = f.x; Ws[cq * 4 + 1][r] = f.y;
      Ws[cq * 4 + 2][r] = f.z; Ws[cq * 4 + 3][r] = f.w;
    }
    __syncthreads();
#pragma unroll
    for (int k = 0; k < 16; ++k) {
      float a[8], b[4];
#pragma unroll
      for (int x = 0; x < 8; ++x) a[x] = Xs[k][it * 8 + x];
#pragma unroll
      for (int y = 0; y < 4; ++y) b[y] = Ws[k][gt * 4 + y];
#pragma unroll
      for (int x = 0; x < 8; ++x)
#pragma unroll
        for (int y = 0; y < 4; ++y)
          acc[x][y] += a[x] * b[y];
    }
    __syncthreads();
  }
  const float4 bs = *(const float4*)(bias + g0 + gt * 4);
#pragma unroll
  for (int x = 0; x < 8; ++x) {
    const int gi = i0 + it * 8 + x;
    const int slot = starts[labels[gi]] + pos[gi];
    float4 o;
    o.x = acc[x][0] + bs.x; o.y = acc[x][1] + bs.y;
    o.z = acc[x][2] + bs.z; o.w = acc[x][3] + bs.w;
    *(float4*)(out + (size_t)slot * G3 + g0 + gt * 4) = o;
  }
}

// ---------------------------------------------------------------------------
// Kernel 3: FUSED 2-layer GRU recurrence + scoring tail. One block (12
// waves) per cluster. SINGLE barrier per step: all LDS state is parity
// double-buffered, every iter reads [par] and writes [par^1] only.
// L1 lags L0 by 2 steps:
//   waves 0-3 : hw0 = W_hh0 . h1(i-1) -> L0 gates -> h1(i)   [iters 0..Lr)
//   waves 4-7 : xw1(i-1) = W_ih1 . h1(i-1) -> xw1buf[par^1]  [iters 1..Lr]
//   waves 8-11: hw1 = W_hh1 . h2(i-3), xw1buf[par] -> h2(i-2) [iters 2..Lr+1]
// xw0 staged in double-buffered CH-step LDS chunks (prefetched one chunk
// ahead; visibility via the regular iter barrier).
// Tail: score + cluster-normalize + position blend for this cluster's
// sentences (ce.v is per-cluster constant; per-sentence 256-dot per wave).
// ---------------------------------------------------------------------------
__global__ __launch_bounds__(768) void gru_fused_k(
    const float* __restrict__ xw0,          // sorted [Mtot+2CH][384] fp32
    const _Float16* __restrict__ pack,      // [3][24][4][64][8] f16 frags
    const float* __restrict__ b_hh0, const float* __restrict__ b_ih0,
    const float* __restrict__ b_ih1, const float* __restrict__ b_hh1,
    const int* __restrict__ starts, const int* __restrict__ len,
    const int* __restrict__ order, const float* __restrict__ sent,
    const float* __restrict__ lin_v, const float* __restrict__ scale,
    const float* __restrict__ lin_b, float* __restrict__ out) {
  const int c = blockIdx.x;
  const int t = threadIdx.x;
  const int wv = t >> 6, lane = t & 63;
  const int group = wv >> 2;                // 0:L0-hw  1:L1-xw  2:L1-hw
  const int v = wv & 3;
  // ---- preload B fragments (96 VGPRs, loop-invariant) ---------------------
  h8 B[6][4];
  {
    const _Float16* mp = pack + (size_t)group * (24 * 4 * 64 * 8);
#pragma unroll
    for (int i = 0; i < 6; ++i) {
      const int nt = (i >> 1) * 8 + 2 * v + (i & 1);
#pragma unroll
      for (int kt = 0; kt < 4; ++kt)
        B[i][kt] = *(const h8*)(mp + ((size_t)(nt * 4 + kt) * 64 + lane) * 8);
    }
  }
  const int L = len[c], start = starts[c];
  const int Lr = (L > 0) ? L : 1;
  const bool use_bih0 = (L == 0);
  // ---- LDS ----------------------------------------------------------------
  __shared__ __align__(16) float xwbuf[2 * CH * G3];     // 48 KB, dbuf chunks
  __shared__ __align__(16) _Float16 hp1[2][2][HH];       // [par][hi/lo]
  __shared__ __align__(16) _Float16 hp2[2][2][HH];
  __shared__ float xw1buf[2][G3];                        // [par]
  __shared__ float ce_s[HH];
  __shared__ float vbuf[G3];
  __shared__ float sc_s[2048];
  __shared__ float sc_red;
  if (t < HH) {
    hp1[0][0][t] = (_Float16)0.f; hp1[0][1][t] = (_Float16)0.f;
    hp2[0][0][t] = (_Float16)0.f; hp2[0][1][t] = (_Float16)0.f;
    hp2[1][0][t] = (_Float16)0.f; hp2[1][1][t] = (_Float16)0.f;
  }
  // prologue: stage chunk 0 into buffer 0
  if (!use_bih0) {
    const float4* src = (const float4*)(xw0 + (size_t)start * G3);
    float4* dst = (float4*)xwbuf;
    dst[t] = src[t];
    dst[t + 768] = src[t + 768];
  }
  // ---- per-lane gate constants (lanes 0..15) ------------------------------
  const int t0 = 32 * v + (lane & 15), t1 = t0 + 16;
  float bhr0 = 0.f, bhz0 = 0.f, bhn0 = 0.f, bhr1 = 0.f, bhz1 = 0.f, bhn1 = 0.f;
  float bir0 = 0.f, biz0 = 0.f, bin0 = 0.f, bir1 = 0.f, biz1 = 0.f, bin1 = 0.f;
  float ha = 0.f, hb = 0.f;                 // h state (h1 for g0, h2 for g2)
  if (lane < 16) {
    if (group == 0) {
      bhr0 = b_hh0[t0]; bhz0 = b_hh0[HH + t0]; bhn0 = b_hh0[2 * HH + t0];
      bhr1 = b_hh0[t1]; bhz1 = b_hh0[HH + t1]; bhn1 = b_hh0[2 * HH + t1];
      if (use_bih0) {
        bir0 = b_ih0[t0]; biz0 = b_ih0[HH + t0]; bin0 = b_ih0[2 * HH + t0];
        bir1 = b_ih0[t1]; biz1 = b_ih0[HH + t1]; bin1 = b_ih0[2 * HH + t1];
      }
    } else if (group == 2) {
      bhr0 = b_hh1[t0]; bhz0 = b_hh1[HH + t0]; bhn0 = b_hh1[2 * HH + t0];
      bhr1 = b_hh1[t1]; bhz1 = b_hh1[HH + t1]; bhn1 = b_hh1[2 * HH + t1];
      bir0 = b_ih1[t0]; biz0 = b_ih1[HH + t0]; bin0 = b_ih1[2 * HH + t0];
      bir1 = b_ih1[t1]; biz1 = b_ih1[HH + t1]; bin1 = b_ih1[2 * HH + t1];
    }
  }
  __syncthreads();   // init + chunk-0 staging visible
  const int q = lane >> 4;
  const int hs = ((lane & 15) == 0) ? 0 : 1;   // A row0 = h_hi, rows>=1 = h_lo
  for (int iter = 0; iter < Lr + 2; ++iter) {
    const int par = iter & 1;
    // ---- prefetch next xw0 chunk into the other buffer -------------------
    if (!use_bih0 && (iter & (CH - 1)) == 0 && iter + CH < Lr) {
      const float4* src = (const float4*)(xw0 + (size_t)(start + iter + CH) * G3);
      float4* dst = (float4*)(xwbuf + ((((iter >> 4) + 1) & 1) ? CH * G3 : 0));
      dst[t] = src[t];
      dst[t + 768] = src[t + 768];
    }
    // ---- MFMA phase ------------------------------------------------------
    const bool mfma_on = (group == 0) ? (iter < Lr)
                        : (group == 1) ? (iter >= 1 && iter <= Lr)
                                       : (iter >= 2);
    f32x4 acc[6];
    if (mfma_on) {
      const _Float16* hbase = (group == 2) ? hp2[par][hs] : hp1[par][hs];
      h8 A[4];
#pragma unroll
      for (int kt = 0; kt < 4; ++kt)
        A[kt] = *(const h8*)(hbase + kt * 32 + q * 8);
#pragma unroll
      for (int i = 0; i < 6; ++i) {
        f32x4 a = {0.f, 0.f, 0.f, 0.f};
#pragma unroll
        for (int kt = 0; kt < 4; ++kt)
          a = __builtin_amdgcn_mfma_f32_16x16x32_f16(A[kt], B[i][kt], a, 0, 0, 0);
        acc[i] = a;
      }
      if (group == 1 && lane < 16) {        // publish xw1(i-1) -> [par^1]
        float* xo = xw1buf[par ^ 1];
        xo[t0]          = acc[0][0] + acc[0][1];
        xo[t1]          = acc[1][0] + acc[1][1];
        xo[HH + t0]     = acc[2][0] + acc[2][1];
        xo[HH + t1]     = acc[3][0] + acc[3][1];
        xo[2 * HH + t0] = acc[4][0] + acc[4][1];
        xo[2 * HH + t1] = acc[5][0] + acc[5][1];
      }
      // ---- wave-local gates (lanes 0..15, groups 0 and 2) ----------------
      if (lane < 16 && group != 1) {
        float xr0, xz0, xn0, xr1, xz1, xn1;
        if (group == 0) {
          const float* xrow = xwbuf + ((iter >> 4) & 1) * (CH * G3)
                                    + (iter & (CH - 1)) * G3;
          xr0 = use_bih0 ? bir0 : xrow[t0];
          xz0 = use_bih0 ? biz0 : xrow[HH + t0];
          xn0 = use_bih0 ? bin0 : xrow[2 * HH + t0];
          xr1 = use_bih0 ? bir1 : xrow[t1];
          xz1 = use_bih0 ? biz1 : xrow[HH + t1];
          xn1 = use_bih0 ? bin1 : xrow[2 * HH + t1];
        } else {
          const float* xi = xw1buf[par];    // xw1(i-2), published 1 iter ago
          xr0 = xi[t0] + bir0;
          xz0 = xi[HH + t0] + biz0;
          xn0 = xi[2 * HH + t0] + bin0;
          xr1 = xi[t1] + bir1;
          xz1 = xi[HH + t1] + biz1;
          xn1 = xi[2 * HH + t1] + bin1;
        }
        const float hwr0 = acc[0][0] + acc[0][1];
        const float hwr1 = acc[1][0] + acc[1][1];
        const float hwz0 = acc[2][0] + acc[2][1];
        const float hwz1 = acc[3][0] + acc[3][1];
        const float hwn0 = acc[4][0] + acc[4][1];
        const float hwn1 = acc[5][0] + acc[5][1];
        const float r0 = 1.f / (1.f + __expf(-(xr0 + bhr0 + hwr0)));
        const float z0 = 1.f / (1.f + __expf(-(xz0 + bhz0 + hwz0)));
        const float r1 = 1.f / (1.f + __expf(-(xr1 + bhr1 + hwr1)));
        const float z1 = 1.f / (1.f + __expf(-(xz1 + bhz1 + hwz1)));
        float tg0 = xn0 + r0 * (bhn0 + hwn0);
        float tg1 = xn1 + r1 * (bhn1 + hwn1);
        tg0 = fminf(fmaxf(tg0, -15.f), 15.f);
        tg1 = fminf(fmaxf(tg1, -15.f), 15.f);
        const float e0 = __expf(2.f * tg0), e1 = __expf(2.f * tg1);
        const float n0 = (e0 - 1.f) / (e0 + 1.f);
        const float n1 = (e1 - 1.f) / (e1 + 1.f);
        ha = (1.f - z0) * n0 + z0 * ha;
        hb = (1.f - z1) * n1 + z1 * hb;
        const _Float16 hiA = (_Float16)ha, hiB = (_Float16)hb;
        _Float16 (*hp)[HH] = (group == 0) ? hp1[par ^ 1] : hp2[par ^ 1];
        hp[0][t0] = hiA; hp[1][t0] = (_Float16)(ha - (float)hiA);
        hp[0][t1] = hiB; hp[1][t1] = (_Float16)(hb - (float)hiB);
      }
    }
    __syncthreads();   // the ONLY barrier: publish [par^1], protect [par]
  }
  // ---- scoring tail (cluster c's sentences) -------------------------------
  if (L == 0) return;
  if (group == 2 && lane < 16) { ce_s[t0] = ha; ce_s[t1] = hb; }
  if (t < G3) vbuf[t] = lin_v[t];
  __syncthreads();
  if (wv == 0) {   // ce . v[256:384] (per-cluster constant)
    float cd = ce_s[lane] * vbuf[DD + lane] + ce_s[64 + lane] * vbuf[DD + 64 + lane];
    for (int off = 32; off; off >>= 1) cd += __shfl_down(cd, off);
    if (lane == 0) sc_red = cd;
  }
  __syncthreads();
  const float cedot = sc_red;
  const float sc = scale[0], lb = lin_b[0];
  const int Lc = (L < 2048) ? L : 2048;
  for (int p = wv; p < Lc; p += 12) {
    const int i = order[c * NN + p];
    const float4 a = *(const float4*)(sent + (size_t)i * DD + lane * 4);
    const float4 b = ((const float4*)vbuf)[lane];
    float d = a.x * b.x + a.y * b.y + a.z * b.z + a.w * b.w;
    for (int off = 32; off; off >>= 1) d += __shfl_down(d, off);
    if (lane == 0) sc_s[p] = tanhf(sc * (d + cedot) + lb);
  }
  __syncthreads();
  if (wv == 0) {   // cluster sum -> 1/sum
    float s = 0.f;
    for (int p = lane; p < Lc; p += 64) s += sc_s[p];
    for (int off = 32; off; off >>= 1) s += __shfl_down(s, off);
    if (lane == 0) sc_red = 1.f / s;
  }
  __syncthreads();
  const float inv = sc_red;
  for (int p = t; p < Lc; p += 768) {
    const int i = order[c * NN + p];
    float ps = __expf(-(float)(i + 1) * 0.0625f);   // 1/4096^(1/3) == 1/16
    ps = fmaxf(0.5f, ps);
    out[i] = 0.5f * (sc_s[p] * inv) + 0.5f * ps;
  }
}

// ---------------------------------------------------------------------------
extern "C" void kernel_launch(void* const* d_in, const int* in_sizes, int n_in,
                              void* d_out, int out_size, void* d_ws, size_t ws_size,
                              hipStream_t stream) {
  const float* sent   = (const float*)d_in[0];
  const int*   labels = (const int*)d_in[1];
  const float* W_ih0  = (const float*)d_in[2];
  const float* W_hh0  = (const float*)d_in[3];
  const float* b_ih0  = (const float*)d_in[4];
  const float* b_hh0  = (const float*)d_in[5];
  const float* W_ih1  = (const float*)d_in[6];
  const float* W_hh1  = (const float*)d_in[7];
  const float* b_ih1  = (const float*)d_in[8];
  const float* b_hh1  = (const float*)d_in[9];
  const float* lin_v  = (const float*)d_in[10];
  const float* lin_g  = (const float*)d_in[11];
  const float* lin_b  = (const float*)d_in[12];
  float* out = (float*)d_out;

  char* ws = (char*)d_ws;
  size_t off = 0;
  auto alloc = [&](size_t bytes) -> void* {
    void* p = ws + off;
    off = (off + bytes + 255) & ~(size_t)255;
    return p;
  };
  int*   order  = (int*)  alloc((size_t)KK * NN * sizeof(int));
  int*   pos    = (int*)  alloc(NN * sizeof(int));
  int*   len    = (int*)  alloc(KK * sizeof(int));
  int*   starts = (int*)  alloc((KK + 1) * sizeof(int));
  float* scale  = (float*)alloc(sizeof(float));
  _Float16* pack = (_Float16*)alloc((size_t)18432 * 8 * sizeof(_Float16));
  float* xw     = (float*)alloc((size_t)(NN + KK + 2 * CH) * G3 * sizeof(float));
  (void)ws_size; (void)in_sizes; (void)n_in; (void)out_size;

  setup_k<<<dim3(19), dim3(1024), 0, stream>>>(
      labels, lin_v, lin_g, W_hh0, W_ih1, W_hh1,
      order, pos, len, starts, scale, pack);
  gemm_ih_k<<<dim3(32, 6), dim3(256), 0, stream>>>(
      sent, W_ih0, b_ih0, labels, pos, starts, xw);
  gru_fused_k<<<dim3(KK), dim3(768), 0, stream>>>(
      xw, pack, b_hh0, b_ih0, b_ih1, b_hh1, starts, len,
      order, sent, lin_v, scale, lin_b, out);
}